// Round 7
// baseline (120.846 us; speedup 1.0000x reference)
//
#include <hip/hip_runtime.h>
#include <math.h>

#define BB 4
#define SS 4096
#define DK 5
#define TK 1024
#define NT 256
// (1/sqrt(5)) * log2(e) folded into all score terms so p = v_exp_f32(score)
#define LAM (0.44721359549995793f * 1.4426950408889634f)

typedef float v2f __attribute__((ext_vector_type(2)));

__device__ __forceinline__ float fast_exp2(float x) {
#if __has_builtin(__builtin_amdgcn_exp2f)
    return __builtin_amdgcn_exp2f(x);
#else
    float r; asm("v_exp_f32 %0, %1" : "=v"(r) : "v"(x)); return r;
#endif
}

// Packed fp32: compiler selects v_pk_fma_f32 on gfx90a+ for <2 x float> fma.
__device__ __forceinline__ v2f pk_fma(v2f a, v2f b, v2f c) {
    return __builtin_elementwise_fma(a, b, c);
}

// async global->LDS, 16B per lane (dest lane-contiguous)
#define GLOAD16(gp, lp)                                                        \
    __builtin_amdgcn_global_load_lds(                                          \
        (const __attribute__((address_space(1))) unsigned int*)(gp),           \
        (__attribute__((address_space(3))) unsigned int*)(lp), 16, 0, 0)

// ---------------------------------------------------------------------------
// Kernel 1: K' = [x0,x1,x2,g], g = LAM*(Wk^T bq)·x  (bq cross-term; per-row
// bias terms cancel in numerator/denominator). V^T = [B][5][S].
// ---------------------------------------------------------------------------
__global__ __launch_bounds__(NT) void proj_kv(
    const float* __restrict__ x,
    const float* __restrict__ Wk, const float* __restrict__ bq,
    const float* __restrict__ Wv, const float* __restrict__ bv,
    float* __restrict__ Kt, float* __restrict__ Vt)
{
    int gid = blockIdx.x * NT + threadIdx.x;
    if (gid >= BB * SS) return;
    int b = gid >> 12;
    int s = gid & (SS - 1);
    float x0 = x[gid * 3 + 0];
    float x1 = x[gid * 3 + 1];
    float x2 = x[gid * 3 + 2];

    float u0 = 0.f, u1 = 0.f, u2 = 0.f;   // u = Wk^T bq
#pragma unroll
    for (int d = 0; d < DK; ++d) {
        float bqd = bq[d];
        u0 = fmaf(Wk[d * 3 + 0], bqd, u0);
        u1 = fmaf(Wk[d * 3 + 1], bqd, u1);
        u2 = fmaf(Wk[d * 3 + 2], bqd, u2);
    }
    float g = LAM * (u0 * x0 + u1 * x1 + u2 * x2);

    float* KtB = Kt + (size_t)b * 4 * SS;
    KtB[0 * SS + s] = x0;
    KtB[1 * SS + s] = x1;
    KtB[2 * SS + s] = x2;
    KtB[3 * SS + s] = g;

#pragma unroll
    for (int d = 0; d < DK; ++d) {
        float vv = fmaf(Wv[d * 3 + 0], x0, fmaf(Wv[d * 3 + 1], x1, fmaf(Wv[d * 3 + 2], x2, bv[d])));
        Vt[((size_t)b * DK + d) * SS + s] = vv;
    }
}

// ---------------------------------------------------------------------------
// Kernel 2: attention. Every wave owns 2 low + 2 high (mirror) rows so all
// waves in all blocks do identical per-tile work (no barrier stranding, no
// inter-block imbalance). Per-row FUSED score->exp->l->V-accumulate keeps
// register liveness short (R6's cross-region pA/pB arrays caused a scratch
// spill: VGPR 64 + 111MB FETCH). All gating conditions wave-uniform.
// score = a_q·x_k + g_k (pre-scaled), p = exp2(score).
// Denominator: all keys; numerator: keys <= row (mask-after-softmax).
// ---------------------------------------------------------------------------
__global__ __launch_bounds__(NT, 4) void attn(
    const float* __restrict__ x,
    const float* __restrict__ Wq, const float* __restrict__ Wk,
    const float* __restrict__ Kt, const float* __restrict__ Vt,
    float* __restrict__ out)
{
    __shared__ float kls[4][TK];
    __shared__ float vls[DK][TK];

    const int tid = threadIdx.x;
    const int sub = tid & 63;
    const int wave = tid >> 6;

    const int b = blockIdx.x >> 8;
    const int i = blockIdx.x & 255;
    const int lowRow  = i * 8;
    const int highRow = (511 - i) * 8;
    const int lo0 = lowRow + wave * 2;      // rows: lo0, lo0+1, hi0, hi0+1
    const int hi0 = highRow + wave * 2;
    const int rowMaxBlk = highRow + 7;
    const int rows[4] = {lo0, lo0 + 1, hi0, hi0 + 1};

    // M = Wq^T Wk (3x3), uniform
    float M00=0,M01=0,M02=0,M10=0,M11=0,M12=0,M20=0,M21=0,M22=0;
#pragma unroll
    for (int d = 0; d < DK; ++d) {
        float q0 = Wq[d*3+0], q1 = Wq[d*3+1], q2 = Wq[d*3+2];
        float k0 = Wk[d*3+0], k1 = Wk[d*3+1], k2 = Wk[d*3+2];
        M00 = fmaf(q0,k0,M00); M01 = fmaf(q0,k1,M01); M02 = fmaf(q0,k2,M02);
        M10 = fmaf(q1,k0,M10); M11 = fmaf(q1,k1,M11); M12 = fmaf(q1,k2,M12);
        M20 = fmaf(q2,k0,M20); M21 = fmaf(q2,k1,M21); M22 = fmaf(q2,k2,M22);
    }

    // per-row a (broadcast into both packed halves)
    v2f a2[4][3];
#pragma unroll
    for (int r = 0; r < 4; ++r) {
        const float* xr = &x[((size_t)b * SS + rows[r]) * 3];
        float x0 = xr[0], x1 = xr[1], x2 = xr[2];
        float av0 = LAM * (x0*M00 + x1*M10 + x2*M20);
        float av1 = LAM * (x0*M01 + x1*M11 + x2*M21);
        float av2 = LAM * (x0*M02 + x1*M12 + x2*M22);
        a2[r][0] = (v2f){av0, av0};
        a2[r][1] = (v2f){av1, av1};
        a2[r][2] = (v2f){av2, av2};
    }

    float l[4] = {0.f, 0.f, 0.f, 0.f};
    v2f acc2[4][DK];
#pragma unroll
    for (int r = 0; r < 4; ++r)
#pragma unroll
        for (int d = 0; d < DK; ++d) acc2[r][d] = (v2f){0.f, 0.f};

    const float* KtB = Kt + (size_t)b * 4 * SS;
    const float* VtB = Vt + (size_t)b * DK * SS;

    for (int t = 0; t < SS; t += TK) {
        const bool needV = (t <= rowMaxBlk);   // block-uniform
        __syncthreads();
#pragma unroll
        for (int it = 0; it < 4; ++it) {
            int idx = it * NT + tid;
            int d = idx >> 8, c4 = idx & 255;
            GLOAD16(&KtB[(size_t)d * SS + t + c4 * 4], &kls[d][c4 * 4]);
        }
        if (needV) {
#pragma unroll
            for (int it = 0; it < 5; ++it) {
                int idx = it * NT + tid;
                int dd = idx >> 8, c4 = idx & 255;
                GLOAD16(&VtB[(size_t)dd * SS + t + c4 * 4], &vls[dd][c4 * 4]);
            }
        }
        __syncthreads();

#pragma unroll
        for (int j = 0; j < TK / 256; ++j) {
            const int key = j * 256 + sub * 4;
            const int cstart = t + j * 256;     // wave-uniform chunk bounds
            const int cend   = cstart + 255;
            const int kg     = cstart + sub * 4;

            float4 kt0 = *(const float4*)&kls[0][key];
            float4 kt1 = *(const float4*)&kls[1][key];
            float4 kt2 = *(const float4*)&kls[2][key];
            float4 kt3 = *(const float4*)&kls[3][key];
            v2f kA0 = ((v2f*)&kt0)[0], kB0 = ((v2f*)&kt0)[1];
            v2f kA1 = ((v2f*)&kt1)[0], kB1 = ((v2f*)&kt1)[1];
            v2f kA2 = ((v2f*)&kt2)[0], kB2 = ((v2f*)&kt2)[1];
            v2f gA  = ((v2f*)&kt3)[0], gB  = ((v2f*)&kt3)[1];

            // V loaded once per chunk iff any of this wave's rows needs it
            v2f vA[DK], vB[DK];
            if (cstart <= hi0 + 1) {
#pragma unroll
                for (int d = 0; d < DK; ++d) {
                    float4 vt = *(const float4*)&vls[d][key];
                    vA[d] = ((v2f*)&vt)[0]; vB[d] = ((v2f*)&vt)[1];
                }
            }

            // fused per-row: score -> exp -> l -> (gated) V accumulate
#pragma unroll
            for (int r = 0; r < 4; ++r) {
                const int row = rows[r];
                v2f scA = pk_fma(a2[r][0], kA0, pk_fma(a2[r][1], kA1, pk_fma(a2[r][2], kA2, gA)));
                v2f scB = pk_fma(a2[r][0], kB0, pk_fma(a2[r][1], kB1, pk_fma(a2[r][2], kB2, gB)));
                v2f pA, pB;
                pA.x = fast_exp2(scA.x); pA.y = fast_exp2(scA.y);
                pB.x = fast_exp2(scB.x); pB.y = fast_exp2(scB.y);
                v2f ps = pA + pB;
                l[r] += ps.x + ps.y;

                if (cend <= row) {
                    // all keys in chunk causal: unmasked accumulate
#pragma unroll
                    for (int d = 0; d < DK; ++d) {
                        acc2[r][d] = pk_fma(pA, vA[d], acc2[r][d]);
                        acc2[r][d] = pk_fma(pB, vB[d], acc2[r][d]);
                    }
                } else if (cstart <= row) {
                    // boundary chunk for this row: masked accumulate
                    v2f pmA, pmB;
                    pmA.x = (kg + 0 <= row) ? pA.x : 0.f;
                    pmA.y = (kg + 1 <= row) ? pA.y : 0.f;
                    pmB.x = (kg + 2 <= row) ? pB.x : 0.f;
                    pmB.y = (kg + 3 <= row) ? pB.y : 0.f;
#pragma unroll
                    for (int d = 0; d < DK; ++d) {
                        acc2[r][d] = pk_fma(pmA, vA[d], acc2[r][d]);
                        acc2[r][d] = pk_fma(pmB, vB[d], acc2[r][d]);
                    }
                }
                // else: future-only for this row -> denominator only
            }
        }
    }

    // fold packed halves, then butterfly-reduce across the 64 key-split lanes
#pragma unroll
    for (int r = 0; r < 4; ++r) {
        float lr = l[r];
        float a0 = acc2[r][0].x + acc2[r][0].y;
        float a1 = acc2[r][1].x + acc2[r][1].y;
        float a2_ = acc2[r][2].x + acc2[r][2].y;
        float a3 = acc2[r][3].x + acc2[r][3].y;
        float a4 = acc2[r][4].x + acc2[r][4].y;
#pragma unroll
        for (int off = 32; off >= 1; off >>= 1) {
            lr  += __shfl_xor(lr, off);
            a0  += __shfl_xor(a0, off);
            a1  += __shfl_xor(a1, off);
            a2_ += __shfl_xor(a2_, off);
            a3  += __shfl_xor(a3, off);
            a4  += __shfl_xor(a4, off);
        }
        if (sub < DK) {
            float av = sub == 0 ? a0 : sub == 1 ? a1 : sub == 2 ? a2_ : sub == 3 ? a3 : a4;
            out[((size_t)b * SS + rows[r]) * DK + sub] = av / lr;
        }
    }
}

extern "C" void kernel_launch(void* const* d_in, const int* in_sizes, int n_in,
                              void* d_out, int out_size, void* d_ws, size_t ws_size,
                              hipStream_t stream) {
    const float* x  = (const float*)d_in[0];
    const float* Wq = (const float*)d_in[1];
    const float* bq = (const float*)d_in[2];
    const float* Wk = (const float*)d_in[3];
    const float* Wv = (const float*)d_in[5];
    const float* bv = (const float*)d_in[6];
    float* outp = (float*)d_out;

    float* Kt = (float*)d_ws;                       // [B][4][S]  (x0,x1,x2,g)
    float* Vt = Kt + (size_t)BB * 4 * SS;           // [B][5][S]

    proj_kv<<<(BB * SS + NT - 1) / NT, NT, 0, stream>>>(x, Wk, bq, Wv, bv, Kt, Vt);
    attn<<<BB * (SS / 16), NT, 0, stream>>>(x, Wq, Wk, Kt, Vt, outp);
}

// Round 8
// 37.457 us; speedup vs baseline: 3.2262x; 3.2262x over previous
//
#include <hip/hip_runtime.h>
#include <math.h>

#define BB 4
#define SS 4096
#define DK 5
#define TK 1024
#define NT 256
// (1/sqrt(5)) * log2(e) folded into all score terms so p = v_exp_f32(score)
#define LAM (0.44721359549995793f * 1.4426950408889634f)

typedef float v2f __attribute__((ext_vector_type(2)));

__device__ __forceinline__ float fast_exp2(float x) {
#if __has_builtin(__builtin_amdgcn_exp2f)
    return __builtin_amdgcn_exp2f(x);
#else
    float r; asm("v_exp_f32 %0, %1" : "=v"(r) : "v"(x)); return r;
#endif
}

// Packed fp32: compiler selects v_pk_fma_f32 on gfx90a+ for <2 x float> fma.
__device__ __forceinline__ v2f pk_fma(v2f a, v2f b, v2f c) {
    return __builtin_elementwise_fma(a, b, c);
}

// async global->LDS, 16B per lane (dest lane-contiguous)
#define GLOAD16(gp, lp)                                                        \
    __builtin_amdgcn_global_load_lds(                                          \
        (const __attribute__((address_space(1))) unsigned int*)(gp),           \
        (__attribute__((address_space(3))) unsigned int*)(lp), 16, 0, 0)

// ---------------------------------------------------------------------------
// Kernel 1: K' = [x0,x1,x2,g], g = LAM*(Wk^T bq)·x  (bq cross-term; per-row
// bias terms cancel in numerator/denominator). V^T = [B][5][S].
// ---------------------------------------------------------------------------
__global__ __launch_bounds__(NT) void proj_kv(
    const float* __restrict__ x,
    const float* __restrict__ Wk, const float* __restrict__ bq,
    const float* __restrict__ Wv, const float* __restrict__ bv,
    float* __restrict__ Kt, float* __restrict__ Vt)
{
    int gid = blockIdx.x * NT + threadIdx.x;
    if (gid >= BB * SS) return;
    int b = gid >> 12;
    int s = gid & (SS - 1);
    float x0 = x[gid * 3 + 0];
    float x1 = x[gid * 3 + 1];
    float x2 = x[gid * 3 + 2];

    float u0 = 0.f, u1 = 0.f, u2 = 0.f;   // u = Wk^T bq
#pragma unroll
    for (int d = 0; d < DK; ++d) {
        float bqd = bq[d];
        u0 = fmaf(Wk[d * 3 + 0], bqd, u0);
        u1 = fmaf(Wk[d * 3 + 1], bqd, u1);
        u2 = fmaf(Wk[d * 3 + 2], bqd, u2);
    }
    float g = LAM * (u0 * x0 + u1 * x1 + u2 * x2);

    float* KtB = Kt + (size_t)b * 4 * SS;
    KtB[0 * SS + s] = x0;
    KtB[1 * SS + s] = x1;
    KtB[2 * SS + s] = x2;
    KtB[3 * SS + s] = g;

#pragma unroll
    for (int d = 0; d < DK; ++d) {
        float vv = fmaf(Wv[d * 3 + 0], x0, fmaf(Wv[d * 3 + 1], x1, fmaf(Wv[d * 3 + 2], x2, bv[d])));
        Vt[((size_t)b * DK + d) * SS + s] = vv;
    }
}

// ---------------------------------------------------------------------------
// Kernel 2: attention. Every wave owns 2 low + 2 high (mirror) rows: all
// waves in all blocks do identical per-tile work (no barrier stranding, no
// inter-block imbalance). Chunks processed in 2-key halves to halve live
// register pairs; V is loaded and consumed in the SAME wave-uniform scope
// (R6/R7's conditional-load/conditional-use split caused scratch spill:
// VGPR 64, 176 MB FETCH). No launch-bounds occupancy cap.
// score = a_q·x_k + g_k (pre-scaled), p = exp2(score).
// Denominator: all keys; numerator: keys <= row (mask-after-softmax).
// ---------------------------------------------------------------------------
__global__ __launch_bounds__(NT) void attn(
    const float* __restrict__ x,
    const float* __restrict__ Wq, const float* __restrict__ Wk,
    const float* __restrict__ Kt, const float* __restrict__ Vt,
    float* __restrict__ out)
{
    __shared__ float kls[4][TK];
    __shared__ float vls[DK][TK];

    const int tid = threadIdx.x;
    const int sub = tid & 63;
    const int wave = tid >> 6;

    const int b = blockIdx.x >> 8;
    const int i = blockIdx.x & 255;
    const int lowRow  = i * 8;
    const int highRow = (511 - i) * 8;
    const int lo0 = lowRow + wave * 2;      // rows: lo0, lo0+1, hi0, hi0+1
    const int hi0 = highRow + wave * 2;
    const int rowMaxBlk = highRow + 7;
    const int rows[4] = {lo0, lo0 + 1, hi0, hi0 + 1};

    // M = Wq^T Wk (3x3), uniform
    float M00=0,M01=0,M02=0,M10=0,M11=0,M12=0,M20=0,M21=0,M22=0;
#pragma unroll
    for (int d = 0; d < DK; ++d) {
        float q0 = Wq[d*3+0], q1 = Wq[d*3+1], q2 = Wq[d*3+2];
        float k0 = Wk[d*3+0], k1 = Wk[d*3+1], k2 = Wk[d*3+2];
        M00 = fmaf(q0,k0,M00); M01 = fmaf(q0,k1,M01); M02 = fmaf(q0,k2,M02);
        M10 = fmaf(q1,k0,M10); M11 = fmaf(q1,k1,M11); M12 = fmaf(q1,k2,M12);
        M20 = fmaf(q2,k0,M20); M21 = fmaf(q2,k1,M21); M22 = fmaf(q2,k2,M22);
    }

    // per-row a (broadcast into both packed halves)
    v2f a2[4][3];
#pragma unroll
    for (int r = 0; r < 4; ++r) {
        const float* xr = &x[((size_t)b * SS + rows[r]) * 3];
        float x0 = xr[0], x1 = xr[1], x2 = xr[2];
        float av0 = LAM * (x0*M00 + x1*M10 + x2*M20);
        float av1 = LAM * (x0*M01 + x1*M11 + x2*M21);
        float av2 = LAM * (x0*M02 + x1*M12 + x2*M22);
        a2[r][0] = (v2f){av0, av0};
        a2[r][1] = (v2f){av1, av1};
        a2[r][2] = (v2f){av2, av2};
    }

    float l[4] = {0.f, 0.f, 0.f, 0.f};
    v2f acc2[4][DK];
#pragma unroll
    for (int r = 0; r < 4; ++r)
#pragma unroll
        for (int d = 0; d < DK; ++d) acc2[r][d] = (v2f){0.f, 0.f};

    const float* KtB = Kt + (size_t)b * 4 * SS;
    const float* VtB = Vt + (size_t)b * DK * SS;

    for (int t = 0; t < SS; t += TK) {
        const bool needV = (t <= rowMaxBlk);   // block-uniform
        __syncthreads();
#pragma unroll
        for (int it = 0; it < 4; ++it) {
            int idx = it * NT + tid;
            int d = idx >> 8, c4 = idx & 255;
            GLOAD16(&KtB[(size_t)d * SS + t + c4 * 4], &kls[d][c4 * 4]);
        }
        if (needV) {
#pragma unroll
            for (int it = 0; it < 5; ++it) {
                int idx = it * NT + tid;
                int dd = idx >> 8, c4 = idx & 255;
                GLOAD16(&VtB[(size_t)dd * SS + t + c4 * 4], &vls[dd][c4 * 4]);
            }
        }
        __syncthreads();

#pragma unroll
        for (int j = 0; j < TK / 256; ++j) {
            const int cstart = t + j * 256;     // wave-uniform chunk bounds
            const int cend   = cstart + 255;
            const bool anyV  = (cstart <= hi0 + 1);

#pragma unroll
            for (int h = 0; h < 2; ++h) {       // 2 keys per half
                const int keyh = j * 256 + sub * 4 + h * 2;
                const int kgh  = t + keyh;      // global idx of half's 1st key

                v2f k0 = *(const v2f*)&kls[0][keyh];
                v2f k1 = *(const v2f*)&kls[1][keyh];
                v2f k2 = *(const v2f*)&kls[2][keyh];
                v2f g  = *(const v2f*)&kls[3][keyh];

                if (anyV) {
                    // V loaded and consumed in the same scope (no spill)
                    v2f v0 = *(const v2f*)&vls[0][keyh];
                    v2f v1 = *(const v2f*)&vls[1][keyh];
                    v2f v2 = *(const v2f*)&vls[2][keyh];
                    v2f v3 = *(const v2f*)&vls[3][keyh];
                    v2f v4 = *(const v2f*)&vls[4][keyh];
#pragma unroll
                    for (int r = 0; r < 4; ++r) {
                        const int row = rows[r];
                        v2f sc = pk_fma(a2[r][0], k0,
                                 pk_fma(a2[r][1], k1,
                                 pk_fma(a2[r][2], k2, g)));
                        v2f p;
                        p.x = fast_exp2(sc.x); p.y = fast_exp2(sc.y);
                        l[r] += p.x + p.y;
                        if (cend <= row) {          // full accumulate
                            acc2[r][0] = pk_fma(p, v0, acc2[r][0]);
                            acc2[r][1] = pk_fma(p, v1, acc2[r][1]);
                            acc2[r][2] = pk_fma(p, v2, acc2[r][2]);
                            acc2[r][3] = pk_fma(p, v3, acc2[r][3]);
                            acc2[r][4] = pk_fma(p, v4, acc2[r][4]);
                        } else if (cstart <= row) { // boundary: masked
                            v2f pm;
                            pm.x = (kgh + 0 <= row) ? p.x : 0.f;
                            pm.y = (kgh + 1 <= row) ? p.y : 0.f;
                            acc2[r][0] = pk_fma(pm, v0, acc2[r][0]);
                            acc2[r][1] = pk_fma(pm, v1, acc2[r][1]);
                            acc2[r][2] = pk_fma(pm, v2, acc2[r][2]);
                            acc2[r][3] = pk_fma(pm, v3, acc2[r][3]);
                            acc2[r][4] = pk_fma(pm, v4, acc2[r][4]);
                        }
                        // else: future-only for this row -> denominator only
                    }
                } else {
                    // denominator-only chunk for all 4 rows
#pragma unroll
                    for (int r = 0; r < 4; ++r) {
                        v2f sc = pk_fma(a2[r][0], k0,
                                 pk_fma(a2[r][1], k1,
                                 pk_fma(a2[r][2], k2, g)));
                        v2f p;
                        p.x = fast_exp2(sc.x); p.y = fast_exp2(sc.y);
                        l[r] += p.x + p.y;
                    }
                }
            }
        }
    }

    // fold packed halves, then butterfly-reduce across the 64 key-split lanes
#pragma unroll
    for (int r = 0; r < 4; ++r) {
        float lr = l[r];
        float a0 = acc2[r][0].x + acc2[r][0].y;
        float a1 = acc2[r][1].x + acc2[r][1].y;
        float a2_ = acc2[r][2].x + acc2[r][2].y;
        float a3 = acc2[r][3].x + acc2[r][3].y;
        float a4 = acc2[r][4].x + acc2[r][4].y;
#pragma unroll
        for (int off = 32; off >= 1; off >>= 1) {
            lr  += __shfl_xor(lr, off);
            a0  += __shfl_xor(a0, off);
            a1  += __shfl_xor(a1, off);
            a2_ += __shfl_xor(a2_, off);
            a3  += __shfl_xor(a3, off);
            a4  += __shfl_xor(a4, off);
        }
        if (sub < DK) {
            float av = sub == 0 ? a0 : sub == 1 ? a1 : sub == 2 ? a2_ : sub == 3 ? a3 : a4;
            out[((size_t)b * SS + rows[r]) * DK + sub] = av / lr;
        }
    }
}

extern "C" void kernel_launch(void* const* d_in, const int* in_sizes, int n_in,
                              void* d_out, int out_size, void* d_ws, size_t ws_size,
                              hipStream_t stream) {
    const float* x  = (const float*)d_in[0];
    const float* Wq = (const float*)d_in[1];
    const float* bq = (const float*)d_in[2];
    const float* Wk = (const float*)d_in[3];
    const float* Wv = (const float*)d_in[5];
    const float* bv = (const float*)d_in[6];
    float* outp = (float*)d_out;

    float* Kt = (float*)d_ws;                       // [B][4][S]  (x0,x1,x2,g)
    float* Vt = Kt + (size_t)BB * 4 * SS;           // [B][5][S]

    proj_kv<<<(BB * SS + NT - 1) / NT, NT, 0, stream>>>(x, Wk, bq, Wv, bv, Kt, Vt);
    attn<<<BB * (SS / 16), NT, 0, stream>>>(x, Wq, Wk, Kt, Vt, outp);
}